// Round 4
// baseline (361.523 us; speedup 1.0000x reference)
//
#include <hip/hip_runtime.h>
#include <cstdint>
#include <cstddef>

#define B_ 8
#define N_ 2048
#define H_ 8
#define D_ 32
#define U_ 256

typedef _Float16 half8 __attribute__((ext_vector_type(8)));
typedef _Float16 half4 __attribute__((ext_vector_type(4)));
typedef float float4v __attribute__((ext_vector_type(4)));

__device__ __forceinline__ float fast_exp2(float x) {
#if __has_builtin(__builtin_amdgcn_exp2f)
  return __builtin_amdgcn_exp2f(x);
#else
  return exp2f(x);
#endif
}

// ---------------------------------------------------------------------------
// K0: prep. blocks 0..511: X fp32->fp16 (each thread 32 elems).
// blocks 512..515: transpose W{q,k,v,o} 256x256 -> WT[m][n][k] fp16,
// q-scale log2(e)/sqrt(32) folded into WTq.
// ---------------------------------------------------------------------------
__global__ __launch_bounds__(256)
void k_prep(const float* __restrict__ X,
            const float* __restrict__ Wq, const float* __restrict__ Wk,
            const float* __restrict__ Wv, const float* __restrict__ Wo,
            _Float16* __restrict__ Xh, _Float16* __restrict__ WT)
{
  const int bid = blockIdx.x, tid = threadIdx.x;
  if (bid < 512) {
    const size_t base = ((size_t)bid * 256 + tid) * 32;
    const float* src = X + base;
    _Float16* dst = Xh + base;
#pragma unroll
    for (int i = 0; i < 4; ++i) {
      float4v a = *(const float4v*)(src + i * 8);
      float4v b = *(const float4v*)(src + i * 8 + 4);
      half8 h;
      h[0] = (_Float16)a[0]; h[1] = (_Float16)a[1];
      h[2] = (_Float16)a[2]; h[3] = (_Float16)a[3];
      h[4] = (_Float16)b[0]; h[5] = (_Float16)b[1];
      h[6] = (_Float16)b[2]; h[7] = (_Float16)b[3];
      *(half8*)(dst + i * 8) = h;
    }
  } else {
    const int m = bid - 512; // 0=q 1=k 2=v 3=o
    const float* W = (m == 0) ? Wq : (m == 1) ? Wk : (m == 2) ? Wv : Wo;
    const float scale = (m == 0) ? 0.25505413f : 1.0f; // log2(e)/sqrt(32)
    _Float16* T = WT + (size_t)m * U_ * U_;
    __shared__ _Float16 Ts[64][72];
    const int r = tid >> 2, seg = tid & 3;
    for (int t = 0; t < 16; ++t) {
      const int k0 = (t >> 2) * 64, n0 = (t & 3) * 64;
      float4v a[4];
      const float* s = W + (size_t)(k0 + r) * U_ + n0 + seg * 16;
#pragma unroll
      for (int i = 0; i < 4; ++i) a[i] = *(const float4v*)(s + i * 4);
      __syncthreads();
#pragma unroll
      for (int i = 0; i < 4; ++i)
#pragma unroll
        for (int j = 0; j < 4; ++j)
          Ts[seg * 16 + i * 4 + j][r] = (_Float16)(a[i][j] * scale);
      __syncthreads();
      _Float16* d = T + (size_t)(n0 + r) * U_ + k0 + seg * 16;
      *(half8*)d       = *(const half8*)&Ts[r][seg * 16];
      *(half8*)(d + 8) = *(const half8*)&Ts[r][seg * 16 + 8];
    }
  }
}

// ---------------------------------------------------------------------------
// K1: QKV projection as an LDS-free, barrier-free register GEMM.
// grid (6,128): proj = bx>>1, 128-col half = bx&1; 128 rows/block, K=256.
// A-frags direct from Xh (contiguous 8 halves), B-frags direct from WT
// (L2-resident, 512 KB). V written transposed VT[b][u][n] via LDS (epilogue only).
// ---------------------------------------------------------------------------
__global__ __launch_bounds__(256, 2)
void k_qkv(const _Float16* __restrict__ Xh, const _Float16* __restrict__ WT,
           _Float16* __restrict__ Qg, _Float16* __restrict__ Kg,
           _Float16* __restrict__ VTg)
{
  __shared__ __attribute__((aligned(16))) _Float16 tr[128 * 136]; // proj==2 only

  const int tid  = threadIdx.x;
  const int lane = tid & 63;
  const int w    = tid >> 6;
  const int c    = lane & 15;
  const int qd   = lane >> 4;
  const int bx   = blockIdx.x;
  const int proj = bx >> 1;
  const int n0l  = (bx & 1) * 128;
  const int m0   = blockIdx.y * 128;

  const _Float16* Wp = WT + (size_t)proj * U_ * U_;
  const _Float16* arow0 = Xh + (size_t)(m0 + w * 32 + c) * U_ + qd * 8;
  const _Float16* arow1 = arow0 + (size_t)16 * U_;
  const _Float16* brow  = Wp + (size_t)(n0l + c) * U_ + qd * 8;

  const float4v zero4 = {0.f, 0.f, 0.f, 0.f};
  float4v acc[2][8];
#pragma unroll
  for (int i = 0; i < 2; ++i)
#pragma unroll
    for (int j = 0; j < 8; ++j) acc[i][j] = zero4;

#pragma unroll 2
  for (int ks = 0; ks < 8; ++ks) {
    const int k0 = ks * 32;
    half8 af0 = *(const half8*)(arow0 + k0);
    half8 af1 = *(const half8*)(arow1 + k0);
    half8 bf[8];
#pragma unroll
    for (int nt = 0; nt < 8; ++nt)
      bf[nt] = *(const half8*)(brow + (size_t)nt * 16 * U_ + k0);
#pragma unroll
    for (int nt = 0; nt < 8; ++nt) {
      acc[0][nt] = __builtin_amdgcn_mfma_f32_16x16x32_f16(af0, bf[nt], acc[0][nt], 0, 0, 0);
      acc[1][nt] = __builtin_amdgcn_mfma_f32_16x16x32_f16(af1, bf[nt], acc[1][nt], 0, 0, 0);
    }
  }

  const int b   = m0 >> 11;
  const int nb0 = m0 & (N_ - 1);
  if (proj < 2) {
    _Float16* Og = (proj == 0) ? Qg : Kg;
#pragma unroll
    for (int mt = 0; mt < 2; ++mt)
#pragma unroll
      for (int nt = 0; nt < 8; ++nt)
#pragma unroll
        for (int r = 0; r < 4; ++r) {
          const int rowl = w * 32 + mt * 16 + qd * 4 + r;
          Og[(size_t)(b * N_ + nb0 + rowl) * U_ + n0l + nt * 16 + c] = (_Float16)acc[mt][nt][r];
        }
  } else {
#pragma unroll
    for (int mt = 0; mt < 2; ++mt)
#pragma unroll
      for (int nt = 0; nt < 8; ++nt)
#pragma unroll
        for (int r = 0; r < 4; ++r)
          tr[(nt * 16 + c) * 136 + w * 32 + mt * 16 + qd * 4 + r] = (_Float16)acc[mt][nt][r];
    __syncthreads();
    const int u = tid >> 1;
    const int seg = tid & 1;
    _Float16* dst = VTg + (size_t)(b * U_ + n0l + u) * N_ + nb0 + seg * 64;
#pragma unroll
    for (int i = 0; i < 8; ++i)
      *(half8*)(dst + i * 8) = *(const half8*)&tr[u * 136 + seg * 64 + i * 8];
  }
}

// ---------------------------------------------------------------------------
// K2: fused masked flash attention. Tq=32, Tk=32, grid 512 (2 wg/CU,
// 16 waves/CU), block 512 = 8 waves = 8 heads. Double-buffered LDS pipeline,
// fixed-bias softmax p = exp2(s-8) (no online max; bias cancels in p/l).
// S^T = K*Q^T; P^T exits QK in the B-layout of mfma 16x16x16f16 -> PV in regs.
// LDS: 2*(16896 + 20480) + masks = 75 KB -> exactly 2 wg/CU.
// ---------------------------------------------------------------------------
#define KS_H (32 * 264)
#define VT_H (256 * 40)

struct StageRegs {
  half8 k0, k1, v0, v1;
  int a0, a1;
};

__global__ __launch_bounds__(512, 2)
void k_attn(const _Float16* __restrict__ Qg, const _Float16* __restrict__ Kg,
            const _Float16* __restrict__ VTg, const int* __restrict__ Adj,
            _Float16* __restrict__ Cg)
{
  __shared__ __attribute__((aligned(16))) _Float16 KsB[2][KS_H];   // [32 key][264]
  __shared__ __attribute__((aligned(16))) _Float16 VTsB[2][VT_H];  // [256 u][40]
  __shared__ __attribute__((aligned(8)))  unsigned int maskB[2][32];

  const int tid  = threadIdx.x;
  const int lane = tid & 63;
  const int w    = tid >> 6;   // head
  const int c    = lane & 15;
  const int qd   = lane >> 4;
  const int wg   = blockIdx.x;
  const int b    = wg & 7;     // XCD-L2 affinity: batch <-> XCD
  const int q0   = (wg >> 3) * 32;

  const _Float16* kptr = Kg + (size_t)(b * N_ + (tid >> 4)) * U_ + (tid & 15) * 16;
  const _Float16* vptr = VTg + (size_t)(b * U_ + (tid >> 1)) * N_ + (tid & 1) * 16;
  const int rr = lane >> 5;
  const int kk = lane & 31;
  const int* aptr = Adj + (size_t)(b * N_ + q0 + w * 4 + rr) * N_ + kk;

  half8 qb[2];
#pragma unroll
  for (int nt = 0; nt < 2; ++nt)
    qb[nt] = *(const half8*)(Qg + (size_t)(b * N_ + q0 + nt * 16 + c) * U_ + w * D_ + qd * 8);

  const float4v init4 = {-8.f, -8.f, -8.f, -8.f};
  const float4v zero4 = {0.f, 0.f, 0.f, 0.f};
  float4v acc[2][2];
#pragma unroll
  for (int i = 0; i < 2; ++i)
#pragma unroll
    for (int j = 0; j < 2; ++j) acc[i][j] = zero4;
  float lrow[2] = {0.f, 0.f};

  auto load_tile = [&](int kt) -> StageRegs {
    StageRegs r;
    const _Float16* ks = kptr + (size_t)kt * 32 * U_;
    const _Float16* vs = vptr + (size_t)kt * 32;
    const int* as = aptr + (size_t)kt * 32;
    r.k0 = *(const half8*)ks;  r.k1 = *(const half8*)(ks + 8);
    r.v0 = *(const half8*)vs;  r.v1 = *(const half8*)(vs + 8);
    r.a0 = as[0];
    r.a1 = as[2 * N_];
    return r;
  };
  auto store_tile = [&](const StageRegs& r, int buf) {
    _Float16* kd = &KsB[buf][(tid >> 4) * 264 + (tid & 15) * 16];
    *(half8*)kd = r.k0;  *(half8*)(kd + 8) = r.k1;
    _Float16* vd = &VTsB[buf][(tid >> 1) * 40 + (tid & 1) * 16];
    *(half8*)vd = r.v0;  *(half8*)(vd + 8) = r.v1;
    unsigned long long bm;
    bm = __ballot(r.a0 > 0); if (lane == 0) *(unsigned long long*)&maskB[buf][w * 4 + 0] = bm;
    bm = __ballot(r.a1 > 0); if (lane == 0) *(unsigned long long*)&maskB[buf][w * 4 + 2] = bm;
  };
  auto compute_tile = [&](int buf) {
    half8 ka0 = *(const half8*)&KsB[buf][(0 * 16 + c) * 264 + w * D_ + qd * 8];
    half8 ka1 = *(const half8*)&KsB[buf][(1 * 16 + c) * 264 + w * D_ + qd * 8];
    half4 va[2][2];
#pragma unroll
    for (int mt = 0; mt < 2; ++mt)
#pragma unroll
      for (int kc = 0; kc < 2; ++kc)
        va[mt][kc] = *(const half4*)&VTsB[buf][(w * D_ + mt * 16 + c) * 40 + kc * 16 + qd * 4];
#pragma unroll
    for (int nt = 0; nt < 2; ++nt) {
      float4v s0 = __builtin_amdgcn_mfma_f32_16x16x32_f16(ka0, qb[nt], init4, 0, 0, 0);
      float4v s1 = __builtin_amdgcn_mfma_f32_16x16x32_f16(ka1, qb[nt], init4, 0, 0, 0);
      const unsigned int mq = maskB[buf][nt * 16 + c];
      const unsigned int t0 = mq >> (qd * 4);
      const unsigned int t1 = mq >> (16 + qd * 4);
      half4 pb0, pb1;
      float ls = 0.f;
#pragma unroll
      for (int r = 0; r < 4; ++r) {
        float e0 = fast_exp2(s0[r]);
        float e1 = fast_exp2(s1[r]);
        float p0 = ((t0 >> r) & 1u) ? e0 : 0.f;
        float p1 = ((t1 >> r) & 1u) ? e1 : 0.f;
        ls += p0 + p1;
        pb0[r] = (_Float16)p0;
        pb1[r] = (_Float16)p1;
      }
      lrow[nt] += ls;
      acc[0][nt] = __builtin_amdgcn_mfma_f32_16x16x16f16(va[0][0], pb0, acc[0][nt], 0, 0, 0);
      acc[0][nt] = __builtin_amdgcn_mfma_f32_16x16x16f16(va[0][1], pb1, acc[0][nt], 0, 0, 0);
      acc[1][nt] = __builtin_amdgcn_mfma_f32_16x16x16f16(va[1][0], pb0, acc[1][nt], 0, 0, 0);
      acc[1][nt] = __builtin_amdgcn_mfma_f32_16x16x16f16(va[1][1], pb1, acc[1][nt], 0, 0, 0);
    }
  };

  {
    StageRegs r = load_tile(0);
    store_tile(r, 0);
  }
  __syncthreads();

#pragma unroll 1
  for (int kt = 0; kt < 64; kt += 2) {
    {
      StageRegs r = load_tile(kt + 1);
      compute_tile(0);
      store_tile(r, 1);
    }
    __syncthreads();
    if (kt + 2 < 64) {
      StageRegs r = load_tile(kt + 2);
      compute_tile(1);
      store_tile(r, 0);
    } else {
      compute_tile(1);
    }
    __syncthreads();
  }

  // epilogue: reduce l across qd-groups, normalize, store via LDS
  float rinv[2];
#pragma unroll
  for (int nt = 0; nt < 2; ++nt) {
    float l = lrow[nt];
    l += __shfl_xor(l, 16, 64);
    l += __shfl_xor(l, 32, 64);
    rinv[nt] = (l > 0.f) ? 1.f / l : 0.f;
  }
  _Float16* ctxS = (_Float16*)KsB; // [32 q][264]
#pragma unroll
  for (int mt = 0; mt < 2; ++mt)
#pragma unroll
    for (int nt = 0; nt < 2; ++nt) {
      half4 hv;
#pragma unroll
      for (int r = 0; r < 4; ++r)
        hv[r] = (_Float16)(acc[mt][nt][r] * rinv[nt]);
      *(half4*)&ctxS[(nt * 16 + c) * 264 + w * D_ + mt * 16 + qd * 4] = hv;
    }
  __syncthreads();
  {
    const int row = tid >> 4;      // 0..31
    const int seg = tid & 15;      // 16 halves each
    _Float16* dst = Cg + (size_t)(b * N_ + q0 + row) * U_ + seg * 16;
    *(half8*)dst       = *(const half8*)&ctxS[row * 264 + seg * 16];
    *(half8*)(dst + 8) = *(const half8*)&ctxS[row * 264 + seg * 16 + 8];
  }
}

// ---------------------------------------------------------------------------
// K3: output projection, LDS-free barrier-free register GEMM.
// grid (2,128): 128 cols x 128 rows per block. Out fp32 + bias.
// ---------------------------------------------------------------------------
__global__ __launch_bounds__(256, 2)
void k_out(const _Float16* __restrict__ Cg, const _Float16* __restrict__ WTo,
           const float* __restrict__ bo, float* __restrict__ Out)
{
  const int tid  = threadIdx.x;
  const int lane = tid & 63;
  const int w    = tid >> 6;
  const int c    = lane & 15;
  const int qd   = lane >> 4;
  const int n0l  = blockIdx.x * 128;
  const int m0   = blockIdx.y * 128;

  const _Float16* arow0 = Cg + (size_t)(m0 + w * 32 + c) * U_ + qd * 8;
  const _Float16* arow1 = arow0 + (size_t)16 * U_;
  const _Float16* brow  = WTo + (size_t)(n0l + c) * U_ + qd * 8;

  const float4v zero4 = {0.f, 0.f, 0.f, 0.f};
  float4v acc[2][8];
#pragma unroll
  for (int i = 0; i < 2; ++i)
#pragma unroll
    for (int j = 0; j < 8; ++j) acc[i][j] = zero4;

#pragma unroll 2
  for (int ks = 0; ks < 8; ++ks) {
    const int k0 = ks * 32;
    half8 af0 = *(const half8*)(arow0 + k0);
    half8 af1 = *(const half8*)(arow1 + k0);
    half8 bf[8];
#pragma unroll
    for (int nt = 0; nt < 8; ++nt)
      bf[nt] = *(const half8*)(brow + (size_t)nt * 16 * U_ + k0);
#pragma unroll
    for (int nt = 0; nt < 8; ++nt) {
      acc[0][nt] = __builtin_amdgcn_mfma_f32_16x16x32_f16(af0, bf[nt], acc[0][nt], 0, 0, 0);
      acc[1][nt] = __builtin_amdgcn_mfma_f32_16x16x32_f16(af1, bf[nt], acc[1][nt], 0, 0, 0);
    }
  }

#pragma unroll
  for (int nt = 0; nt < 8; ++nt) {
    const float bias = bo[n0l + nt * 16 + c];
#pragma unroll
    for (int mt = 0; mt < 2; ++mt)
#pragma unroll
      for (int r = 0; r < 4; ++r) {
        const int rowl = w * 32 + mt * 16 + qd * 4 + r;
        Out[(size_t)(m0 + rowl) * U_ + n0l + nt * 16 + c] = acc[mt][nt][r] + bias;
      }
  }
}

// ---------------------------------------------------------------------------
extern "C" void kernel_launch(void* const* d_in, const int* in_sizes, int n_in,
                              void* d_out, int out_size, void* d_ws, size_t ws_size,
                              hipStream_t stream) {
  const float* X   = (const float*)d_in[0];
  const int*   Adj = (const int*)d_in[1];
  const float* Wq  = (const float*)d_in[2];
  const float* Wk  = (const float*)d_in[3];
  const float* Wv  = (const float*)d_in[4];
  const float* Wo  = (const float*)d_in[5];
  const float* bo  = (const float*)d_in[6];
  float* Out = (float*)d_out;

  const size_t elems = (size_t)B_ * N_ * U_; // 4.19M halves = 8.39 MB each
  _Float16* Qg  = (_Float16*)d_ws;
  _Float16* Kg  = Qg + elems;
  _Float16* VTg = Kg + elems;
  _Float16* Xh  = VTg + elems;       // aliased: Cg reuses Xh after k_qkv
  _Float16* Cg  = Xh;
  _Float16* WT  = Xh + elems;        // 4 * 256*256 halves = 512 KB

  k_prep<<<dim3(516), 256, 0, stream>>>(X, Wq, Wk, Wv, Wo, Xh, WT);
  k_qkv<<<dim3(6, 128), 256, 0, stream>>>(Xh, WT, Qg, Kg, VTg);
  k_attn<<<dim3(512), 512, 0, stream>>>(Qg, Kg, VTg, Adj, Cg);
  k_out<<<dim3(2, 128), 256, 0, stream>>>(Cg, WT + 3 * U_ * U_, bo, Out);
}